// Round 1
// baseline (390.477 us; speedup 1.0000x reference)
//
#include <hip/hip_runtime.h>
#include <hip/hip_bf16.h>
#include <math.h>

#define B 32
#define N 8400
#define M 60
#define C 80
#define TOPK_K 13
#define INF_COST 1e8f

// ---------- shared math: MUST be bit-identical across kernels ----------
__device__ __forceinline__ float iou_fn(
    float px1, float py1, float px2, float py2,
    float gx1, float gy1, float gx2, float gy2)
{
#pragma clang fp contract(off)
    float ltx = fmaxf(px1, gx1), lty = fmaxf(py1, gy1);
    float rbx = fminf(px2, gx2), rby = fminf(py2, gy2);
    float wx = fmaxf(rbx - ltx, 0.0f), wy = fmaxf(rby - lty, 0.0f);
    float inter = wx * wy;
    float a1 = (px2 - px1) * (py2 - py1);
    float a2 = (gx2 - gx1) * (gy2 - gy1);
    float uni = fmaxf(a1 + a2 - inter, 1e-6f);
    return inter / uni;
}

__device__ __forceinline__ float cost_fn(
    float iou, float logit,
    float pcx, float pcy, float stride,
    float gcx, float gcy, int validn)
{
#pragma clang fp contract(off)
    if (!validn) return INF_COST;
    float dx = pcx - gcx, dy = pcy - gcy;
    float dist = sqrtf(dx * dx + dy * dy) / stride;
    float soft = exp10f(dist - 3.0f);                 // can overflow to +inf (valid per ref)
    float iouc = -logf(iou + 1e-7f) * 3.0f;
    float sig = 1.0f / (1.0f + expf(-logit));
    float scale = iou - sig;
    float sc2 = scale * scale;
    float bce = fmaxf(logit, 0.0f) - logit * iou + log1pf(expf(-fabsf(logit)));
    float cls = bce * sc2;
    return (cls + iouc) + soft;
}

// ---------- kernel 1: valid_mask[b,n] ----------
__global__ __launch_bounds__(256) void k_valid(
    const float* __restrict__ priors,
    const float* __restrict__ gt_bboxes,
    const float* __restrict__ pad,
    unsigned char* __restrict__ valid)
{
    int idx = blockIdx.x * 256 + threadIdx.x;
    if (idx >= B * N) return;
    int b = idx / N, n = idx % N;
    float px = priors[n * 4 + 0];
    float py = priors[n * 4 + 1];
    const float* g = gt_bboxes + (size_t)b * M * 4;
    const float* pf = pad + (size_t)b * M;
    unsigned char v = 0;
    for (int m = 0; m < M; m++) {
        float x1 = g[m * 4 + 0], y1 = g[m * 4 + 1];
        float x2 = g[m * 4 + 2], y2 = g[m * 4 + 3];
        float mn = fminf(fminf(px - x1, py - y1), fminf(x2 - px, y2 - py));
        if (mn > 0.0f && pf[m] > 0.0f) { v = 1; break; }
    }
    valid[idx] = v;
}

// ---------- kernel 2: per-(b,m) column: dynamic_ks + K-th smallest (cost, n) pair ----------
__global__ __launch_bounds__(256) void k_select(
    const float* __restrict__ pred_bboxes,
    const float* __restrict__ pred_scores,
    const float* __restrict__ priors,
    const int*   __restrict__ gt_labels,
    const float* __restrict__ gt_bboxes,
    const unsigned char* __restrict__ valid,
    float* __restrict__ cK, int* __restrict__ nK)
{
    __shared__ float s_val[N];          // 33.6 KB
    __shared__ float red_v[256];
    __shared__ int   red_i[256];
    __shared__ int   s_K;

    const int bm = blockIdx.x;
    const int b = bm / M, m = bm % M;
    const int tid = threadIdx.x;

    const float gx1 = gt_bboxes[(size_t)bm * 4 + 0];
    const float gy1 = gt_bboxes[(size_t)bm * 4 + 1];
    const float gx2 = gt_bboxes[(size_t)bm * 4 + 2];
    const float gy2 = gt_bboxes[(size_t)bm * 4 + 3];
    const int   label = gt_labels[bm];

    // ---- phase 1: IoU column -> top-13 sum (descending order, like top_k().sum()) ----
    for (int n = tid; n < N; n += 256) {
        const float* pb = pred_bboxes + ((size_t)b * N + n) * 4;
        s_val[n] = iou_fn(pb[0], pb[1], pb[2], pb[3], gx1, gy1, gx2, gy2);
    }
    __syncthreads();

    float ssum = 0.0f;  // meaningful in tid 0 only
    for (int r = 0; r < TOPK_K; r++) {
        float best = -1.0f; int bi = N;
        for (int n = tid; n < N; n += 256) {
            float v = s_val[n];
            if (v > best) { best = v; bi = n; }   // ascending n: keeps first on tie
        }
        red_v[tid] = best; red_i[tid] = bi;
        __syncthreads();
        for (int s = 128; s > 0; s >>= 1) {
            if (tid < s) {
                float v2 = red_v[tid + s]; int i2 = red_i[tid + s];
                if (v2 > red_v[tid] || (v2 == red_v[tid] && i2 < red_i[tid])) {
                    red_v[tid] = v2; red_i[tid] = i2;
                }
            }
            __syncthreads();
        }
        if (tid == 0) { ssum += red_v[0]; s_val[red_i[0]] = -2.0f; }
        __syncthreads();
    }
    if (tid == 0) {
        int k = (int)ssum;          // trunc, matches astype(int32)
        if (k < 1) k = 1;
        s_K = k;
    }

    // ---- phase 2: cost column -> K-th smallest (cost, index) pair ----
    for (int n = tid; n < N; n += 256) {
        const float* pb = pred_bboxes + ((size_t)b * N + n) * 4;
        float iou = iou_fn(pb[0], pb[1], pb[2], pb[3], gx1, gy1, gx2, gy2);
        float logit = pred_scores[((size_t)b * N + n) * C + label];
        float pcx = priors[n * 4 + 0], pcy = priors[n * 4 + 1], st = priors[n * 4 + 2];
        float gcx = (gx1 + gx2) * 0.5f, gcy = (gy1 + gy2) * 0.5f;
        s_val[n] = cost_fn(iou, logit, pcx, pcy, st, gcx, gcy, valid[(size_t)b * N + n]);
    }
    __syncthreads();

    const int K = s_K;
    float ck = 0.0f; int nk = 0;
    for (int r = 0; r < K; r++) {
        float best = INFINITY; int bi = N;
        for (int n = tid; n < N; n += 256) {
            float v = s_val[n];
            // NaN markers (excluded) fail both comparisons
            if (v < best || (v == best && n < bi)) { best = v; bi = n; }
        }
        red_v[tid] = best; red_i[tid] = bi;
        __syncthreads();
        for (int s = 128; s > 0; s >>= 1) {
            if (tid < s) {
                float v2 = red_v[tid + s]; int i2 = red_i[tid + s];
                if (v2 < red_v[tid] || (v2 == red_v[tid] && i2 < red_i[tid])) {
                    red_v[tid] = v2; red_i[tid] = i2;
                }
            }
            __syncthreads();
        }
        ck = red_v[0]; nk = red_i[0];
        if (tid == 0) s_val[nk] = __int_as_float(0x7fc00000); // NaN: never re-selected
        __syncthreads();
    }
    if (tid == 0) { cK[bm] = ck; nK[bm] = nk; }
}

// ---------- kernel 3: per-(b,n) row: matching + outputs ----------
__global__ __launch_bounds__(256) void k_assign(
    const float* __restrict__ pred_bboxes,
    const float* __restrict__ pred_scores,
    const float* __restrict__ priors,
    const int*   __restrict__ gt_labels,
    const float* __restrict__ gt_bboxes,
    const float* __restrict__ pad,
    const unsigned char* __restrict__ valid,
    const float* __restrict__ cK,
    const int*   __restrict__ nK,
    float* __restrict__ out)
{
    int idx = blockIdx.x * 256 + threadIdx.x;
    if (idx >= B * N) return;
    int b = idx / N, n = idx % N;

    const float* pb = pred_bboxes + (size_t)idx * 4;
    float px1 = pb[0], py1 = pb[1], px2 = pb[2], py2 = pb[3];
    float pcx = priors[n * 4 + 0], pcy = priors[n * 4 + 1], st = priors[n * 4 + 2];
    int vn = valid[idx];
    const float* scores = pred_scores + (size_t)idx * C;

    int count = 0, firstm = -1;
    float firstiou = 0.0f;
    float minc = INFINITY; int amin = 0; float aminiou = 0.0f;

    for (int m = 0; m < M; m++) {
        int gi = b * M + m;
        float gx1 = gt_bboxes[(size_t)gi * 4 + 0];
        float gy1 = gt_bboxes[(size_t)gi * 4 + 1];
        float gx2 = gt_bboxes[(size_t)gi * 4 + 2];
        float gy2 = gt_bboxes[(size_t)gi * 4 + 3];
        float iou = iou_fn(px1, py1, px2, py2, gx1, gy1, gx2, gy2);
        int label = gt_labels[gi];
        float logit = scores[label];
        float gcx = (gx1 + gx2) * 0.5f, gcy = (gy1 + gy2) * 0.5f;
        float c = cost_fn(iou, logit, pcx, pcy, st, gcx, gcy, vn);

        if (c < minc) { minc = c; amin = m; aminiou = iou; }  // first-min, like jnp.argmin

        bool gtv = pad[gi] > 0.0f;
        float ckm = cK[gi]; int nkm = nK[gi];
        bool matched = gtv && (c < ckm || (c == ckm && n <= nkm));
        if (matched) { count++; if (firstm < 0) { firstm = m; firstiou = iou; } }
    }

    int mstar; float mi;
    if (count > 1)      { mstar = amin;  mi = aminiou; }
    else if (count == 1){ mstar = firstm; mi = firstiou; }
    else                { mstar = -1;    mi = 0.0f; }

    float* o_lab = out;
    float* o_w   = out + (size_t)B * N;
    float* o_box = out + (size_t)2 * B * N;
    float* o_met = out + (size_t)6 * B * N;

    o_w[idx] = 1.0f;
    if (mstar >= 0) {
        int gi = b * M + mstar;
        o_lab[idx] = (float)gt_labels[gi];
        o_box[(size_t)idx * 4 + 0] = gt_bboxes[(size_t)gi * 4 + 0];
        o_box[(size_t)idx * 4 + 1] = gt_bboxes[(size_t)gi * 4 + 1];
        o_box[(size_t)idx * 4 + 2] = gt_bboxes[(size_t)gi * 4 + 2];
        o_box[(size_t)idx * 4 + 3] = gt_bboxes[(size_t)gi * 4 + 3];
        o_met[idx] = mi;
    } else {
        o_lab[idx] = (float)C;   // background = 80
        o_box[(size_t)idx * 4 + 0] = 0.0f;
        o_box[(size_t)idx * 4 + 1] = 0.0f;
        o_box[(size_t)idx * 4 + 2] = 0.0f;
        o_box[(size_t)idx * 4 + 3] = 0.0f;
        o_met[idx] = 0.0f;
    }
}

extern "C" void kernel_launch(void* const* d_in, const int* in_sizes, int n_in,
                              void* d_out, int out_size, void* d_ws, size_t ws_size,
                              hipStream_t stream) {
    const float* pred_bboxes = (const float*)d_in[0];
    const float* pred_scores = (const float*)d_in[1];
    const float* priors      = (const float*)d_in[2];
    const int*   gt_labels   = (const int*)d_in[3];
    const float* gt_bboxes   = (const float*)d_in[4];
    const float* pad         = (const float*)d_in[5];

    unsigned char* ws = (unsigned char*)d_ws;
    unsigned char* valid = ws;                                   // B*N bytes = 268800
    float* cKp = (float*)(ws + (size_t)B * N);                   // B*M floats
    int*   nKp = (int*)(ws + (size_t)B * N + (size_t)B * M * 4); // B*M ints

    float* out = (float*)d_out;

    dim3 blk(256);
    k_valid <<<(B * N + 255) / 256, blk, 0, stream>>>(priors, gt_bboxes, pad, valid);
    k_select<<<B * M, blk, 0, stream>>>(pred_bboxes, pred_scores, priors, gt_labels,
                                        gt_bboxes, valid, cKp, nKp);
    k_assign<<<(B * N + 255) / 256, blk, 0, stream>>>(pred_bboxes, pred_scores, priors,
                                                      gt_labels, gt_bboxes, pad, valid,
                                                      cKp, nKp, out);
}